// Round 1
// baseline (228.485 us; speedup 1.0000x reference)
//
#include <hip/hip_runtime.h>
#include <stdint.h>

typedef unsigned short u16;
typedef __attribute__((ext_vector_type(8))) short short8v;   // 8 bf16 (4 VGPR) MFMA frag
typedef __attribute__((ext_vector_type(4))) float f32x4;     // MFMA accumulator

#define BATCH   4
#define NSEQ    1024
#define DIMC    768
#define NHEADS  12
#define HDIM    64
#define CQKV    2304
#define MROWS   4096   // BATCH*NSEQ

// ---------- bf16 split helpers (RNE) ----------
__device__ __forceinline__ u16 f2bf(float x) {
    uint32_t u = __float_as_uint(x);
    u += 0x7fffu + ((u >> 16) & 1u);
    return (u16)(u >> 16);
}
__device__ __forceinline__ float bf2f(u16 h) {
    return __uint_as_float(((uint32_t)h) << 16);
}
__device__ __forceinline__ void split_bf16(float x, u16& h, u16& l) {
    h = f2bf(x);
    float r = x - bf2f(h);   // exact (Sterbenz)
    l = f2bf(r);
}

// ---------- async global->LDS (16B/lane, wave-uniform LDS base) ----------
__device__ __forceinline__ void gload_lds16(const void* g, void* l) {
    __builtin_amdgcn_global_load_lds(
        (const __attribute__((address_space(1))) void*)g,
        (__attribute__((address_space(3))) void*)l, 16, 0, 0);
}

// ---------- fp32 -> (hi,lo) bf16 split, vectorized ----------
__global__ void split_kernel(const float* __restrict__ src, u16* __restrict__ hi,
                             u16* __restrict__ lo, int n4) {
    int i = blockIdx.x * blockDim.x + threadIdx.x;
    if (i >= n4) return;
    float4 v = reinterpret_cast<const float4*>(src)[i];
    ushort4 h, l;
    split_bf16(v.x, h.x, l.x);
    split_bf16(v.y, h.y, l.y);
    split_bf16(v.z, h.z, l.z);
    split_bf16(v.w, h.w, l.w);
    reinterpret_cast<ushort4*>(hi)[i] = h;
    reinterpret_cast<ushort4*>(lo)[i] = l;
}

// ---------- split-bf16 GEMM: C[M][N] = A[M][K] * B[N][K]^T  (3-term MFMA) ----------
// EPI==0: qkv epilogue (scale q by 0.125, write q/k hi/lo [B,H,N,hd], v transposed [B,H,hd,N])
// EPI==1: proj epilogue (add bias, fp32 out)
template <int EPI>
__global__ __launch_bounds__(256)
void gemm_split(const u16* __restrict__ Ahi, const u16* __restrict__ Alo,
                const u16* __restrict__ Bhi, const u16* __restrict__ Blo,
                int Kdim,
                u16* __restrict__ qh, u16* __restrict__ ql,
                u16* __restrict__ kh, u16* __restrict__ kl,
                u16* __restrict__ vth, u16* __restrict__ vtl,
                float* __restrict__ outp, const float* __restrict__ bias) {
    __shared__ __align__(16) u16 lA[2][128 * 32];
    __shared__ __align__(16) u16 lB[2][128 * 32];
    const int tid = threadIdx.x;
    const int w = tid >> 6, lane = tid & 63;
    const int l15 = lane & 15, lg = lane >> 4;
    const int m0 = blockIdx.y * 128, n0 = blockIdx.x * 128;
    const int wm = w >> 1, wn = w & 1;

    f32x4 acc[4][4] = {};

    for (int k0 = 0; k0 < Kdim; k0 += 32) {
        __syncthreads();
#pragma unroll
        for (int q = 0; q < 2; ++q) {
            int chunk = (w * 2 + q) * 64 + lane;      // 0..511, 16B chunks
            int row = chunk >> 2, c8 = chunk & 3;     // 4 chunks per 32-elem row
            int goffA = (m0 + row) * Kdim + k0 + c8 * 8;
            int goffB = (n0 + row) * Kdim + k0 + c8 * 8;
            int lbase = (w * 2 + q) * 64 * 8;         // chunk base, u16 units
            gload_lds16(Ahi + goffA, &lA[0][lbase]);
            gload_lds16(Alo + goffA, &lA[1][lbase]);
            gload_lds16(Bhi + goffB, &lB[0][lbase]);
            gload_lds16(Blo + goffB, &lB[1][lbase]);
        }
        __syncthreads();

        short8v ah[4], al[4], bh[4], bl[4];
        const int koff = 8 * lg;
        const int arow = wm * 64 + l15;
        const int brow = wn * 64 + l15;
#pragma unroll
        for (int i = 0; i < 4; ++i) {
            ah[i] = *(const short8v*)&lA[0][(arow + i * 16) * 32 + koff];
            al[i] = *(const short8v*)&lA[1][(arow + i * 16) * 32 + koff];
            bh[i] = *(const short8v*)&lB[0][(brow + i * 16) * 32 + koff];
            bl[i] = *(const short8v*)&lB[1][(brow + i * 16) * 32 + koff];
        }
#pragma unroll
        for (int m = 0; m < 4; ++m)
#pragma unroll
            for (int n = 0; n < 4; ++n) {
                acc[m][n] = __builtin_amdgcn_mfma_f32_16x16x32_bf16(ah[m], bh[n], acc[m][n], 0, 0, 0);
                acc[m][n] = __builtin_amdgcn_mfma_f32_16x16x32_bf16(ah[m], bl[n], acc[m][n], 0, 0, 0);
                acc[m][n] = __builtin_amdgcn_mfma_f32_16x16x32_bf16(al[m], bh[n], acc[m][n], 0, 0, 0);
            }
    }

    // epilogue: D[row][col], row=(lane>>4)*4+reg, col=lane&15 (m89-verified)
    if constexpr (EPI == 0) {
#pragma unroll
        for (int m = 0; m < 4; ++m) {
#pragma unroll
            for (int n = 0; n < 4; ++n) {
                int col = n0 + wn * 64 + n * 16 + l15;     // 0..2303 -> [3,H,hd]
                int qkv = col / 768;
                int rem = col - qkv * 768;
                int h = rem >> 6, d = rem & 63;
#pragma unroll
                for (int r = 0; r < 4; ++r) {
                    int row = m0 + wm * 64 + m * 16 + 4 * lg + r;
                    int b = row >> 10, i = row & 1023;
                    float v = acc[m][n][r];
                    u16 hh, ll;
                    if (qkv == 0) {
                        split_bf16(v * 0.125f, hh, ll);    // fold hd^-0.5 (exact pow2)
                        int o = ((b * NHEADS + h) * NSEQ + i) * HDIM + d;
                        qh[o] = hh; ql[o] = ll;
                    } else if (qkv == 1) {
                        split_bf16(v, hh, ll);
                        int o = ((b * NHEADS + h) * NSEQ + i) * HDIM + d;
                        kh[o] = hh; kl[o] = ll;
                    } else {
                        split_bf16(v, hh, ll);             // V transposed: [B,H,hd,N]
                        int o = ((b * NHEADS + h) * HDIM + d) * NSEQ + i;
                        vth[o] = hh; vtl[o] = ll;
                    }
                }
            }
        }
    } else {
#pragma unroll
        for (int n = 0; n < 4; ++n) {
            int col = n0 + wn * 64 + n * 16 + l15;
            float bv = bias[col];
#pragma unroll
            for (int m = 0; m < 4; ++m)
#pragma unroll
                for (int r = 0; r < 4; ++r) {
                    int row = m0 + wm * 64 + m * 16 + 4 * lg + r;
                    outp[row * DIMC + col] = acc[m][n][r] + bv;
                }
        }
    }
}

// ---------- flash attention with elevation bias, split-bf16 MFMA ----------
__global__ __launch_bounds__(256)
void attn_kernel(const u16* __restrict__ qh, const u16* __restrict__ ql,
                 const u16* __restrict__ kh, const u16* __restrict__ kl,
                 const u16* __restrict__ vth, const u16* __restrict__ vtl,
                 const float* __restrict__ elev, const float* __restrict__ alphap,
                 u16* __restrict__ aoh, u16* __restrict__ aol) {
    __shared__ __align__(16) u16 lK[2][64 * 64];   // [kv][hd] hi/lo
    __shared__ __align__(16) u16 lV[2][64 * 64];   // [hd][kv] hi/lo (V^T tile)
    __shared__ __align__(16) u16 lP[4][2][16 * 64]; // per-wave P round-trip
    const int tid = threadIdx.x;
    const int w = tid >> 6, lane = tid & 63;
    const int l15 = lane & 15, lg = lane >> 4;
    const int q0 = blockIdx.x * 64;
    const int bh = blockIdx.y;
    const int b = bh / NHEADS, h = bh - b * NHEADS;
    const float alpha = alphap[0];
    const size_t base = (size_t)bh * NSEQ * HDIM;   // q/k [B,H,N,hd]
    const size_t vbase = (size_t)bh * HDIM * NSEQ;  // vt  [B,H,hd,N]

    // Q fragments held in registers for the whole block (A-frag: m=lane&15)
    short8v qfh[2], qfl[2];
    {
        int qrow = q0 + w * 16 + l15;
#pragma unroll
        for (int ks = 0; ks < 2; ++ks) {
            size_t off = base + (size_t)qrow * HDIM + ks * 32 + 8 * lg;
            qfh[ks] = *(const short8v*)&qh[off];
            qfl[ks] = *(const short8v*)&ql[off];
        }
    }
    float ei[4];
#pragma unroll
    for (int r = 0; r < 4; ++r) ei[r] = elev[b * NSEQ + q0 + w * 16 + 4 * lg + r];

    float mrun[4], lrun[4];
    f32x4 o[4] = {};
#pragma unroll
    for (int r = 0; r < 4; ++r) { mrun[r] = -1e30f; lrun[r] = 0.f; }

    for (int j0 = 0; j0 < NSEQ; j0 += 64) {
        __syncthreads();
#pragma unroll
        for (int q = 0; q < 2; ++q) {
            int chunk = (w * 2 + q) * 64 + lane;   // 512 chunks of 16B per tile
            int row = chunk >> 3, c8 = chunk & 7;  // 8 chunks per 64-elem row
            int lbase = (w * 2 + q) * 64 * 8;
            size_t kg = base + (size_t)(j0 + row) * HDIM + c8 * 8;
            size_t vg = vbase + (size_t)row * NSEQ + j0 + c8 * 8;
            gload_lds16(kh + kg, &lK[0][lbase]);
            gload_lds16(kl + kg, &lK[1][lbase]);
            gload_lds16(vth + vg, &lV[0][lbase]);
            gload_lds16(vtl + vg, &lV[1][lbase]);
        }
        __syncthreads();

        // S = Q*K^T (scale pre-folded into q)
        f32x4 s[4] = {};
#pragma unroll
        for (int n = 0; n < 4; ++n) {
#pragma unroll
            for (int ks = 0; ks < 2; ++ks) {
                short8v kbh = *(const short8v*)&lK[0][(n * 16 + l15) * 64 + ks * 32 + 8 * lg];
                short8v kbl = *(const short8v*)&lK[1][(n * 16 + l15) * 64 + ks * 32 + 8 * lg];
                s[n] = __builtin_amdgcn_mfma_f32_16x16x32_bf16(qfh[ks], kbh, s[n], 0, 0, 0);
                s[n] = __builtin_amdgcn_mfma_f32_16x16x32_bf16(qfh[ks], kbl, s[n], 0, 0, 0);
                s[n] = __builtin_amdgcn_mfma_f32_16x16x32_bf16(qfl[ks], kbh, s[n], 0, 0, 0);
            }
        }

        // elevation bias + online softmax (rows live in 16-lane groups)
        float sv[4][4];
        float pm[4] = {-1e30f, -1e30f, -1e30f, -1e30f};
#pragma unroll
        for (int n = 0; n < 4; ++n) {
            float ej = elev[b * NSEQ + j0 + n * 16 + l15];
#pragma unroll
            for (int r = 0; r < 4; ++r) {
                float d = (ej - ei[r]) * (1.0f / 1000.0f);
                float bias = fminf(fmaxf(-alpha * fmaxf(d, 0.f), -10.f), 0.f);
                float val = s[n][r] + bias;
                sv[n][r] = val;
                pm[r] = fmaxf(pm[r], val);
            }
        }
#pragma unroll
        for (int r = 0; r < 4; ++r) {
            pm[r] = fmaxf(pm[r], __shfl_xor(pm[r], 1));
            pm[r] = fmaxf(pm[r], __shfl_xor(pm[r], 2));
            pm[r] = fmaxf(pm[r], __shfl_xor(pm[r], 4));
            pm[r] = fmaxf(pm[r], __shfl_xor(pm[r], 8));
        }
        float scl[4], rs[4];
#pragma unroll
        for (int r = 0; r < 4; ++r) {
            float mn = fmaxf(mrun[r], pm[r]);
            scl[r] = __expf(mrun[r] - mn);
            mrun[r] = mn;
            rs[r] = 0.f;
        }
        // P = exp(S - m), split to bf16 hi/lo via wave-private LDS (D->A layout)
#pragma unroll
        for (int n = 0; n < 4; ++n) {
#pragma unroll
            for (int r = 0; r < 4; ++r) {
                float p = __expf(sv[n][r] - mrun[r]);
                rs[r] += p;
                u16 hh, ll;
                split_bf16(p, hh, ll);
                int off = (4 * lg + r) * 64 + n * 16 + l15;
                lP[w][0][off] = hh;
                lP[w][1][off] = ll;
            }
        }
#pragma unroll
        for (int r = 0; r < 4; ++r) {
            rs[r] += __shfl_xor(rs[r], 1);
            rs[r] += __shfl_xor(rs[r], 2);
            rs[r] += __shfl_xor(rs[r], 4);
            rs[r] += __shfl_xor(rs[r], 8);
            lrun[r] = lrun[r] * scl[r] + rs[r];
        }
#pragma unroll
        for (int df = 0; df < 4; ++df)
#pragma unroll
            for (int r = 0; r < 4; ++r) o[df][r] *= scl[r];

        // O += P * V   (A-frag read back from wave-private LDS)
#pragma unroll
        for (int ks = 0; ks < 2; ++ks) {
            short8v pah = *(const short8v*)&lP[w][0][l15 * 64 + ks * 32 + 8 * lg];
            short8v pal = *(const short8v*)&lP[w][1][l15 * 64 + ks * 32 + 8 * lg];
#pragma unroll
            for (int df = 0; df < 4; ++df) {
                short8v vbh = *(const short8v*)&lV[0][(df * 16 + l15) * 64 + ks * 32 + 8 * lg];
                short8v vbl = *(const short8v*)&lV[1][(df * 16 + l15) * 64 + ks * 32 + 8 * lg];
                o[df] = __builtin_amdgcn_mfma_f32_16x16x32_bf16(pah, vbh, o[df], 0, 0, 0);
                o[df] = __builtin_amdgcn_mfma_f32_16x16x32_bf16(pah, vbl, o[df], 0, 0, 0);
                o[df] = __builtin_amdgcn_mfma_f32_16x16x32_bf16(pal, vbh, o[df], 0, 0, 0);
            }
        }
    }

    // normalize + store attention output as split bf16 [B,N,C] for proj GEMM
#pragma unroll
    for (int r = 0; r < 4; ++r) {
        float inv = 1.0f / lrun[r];
        int row = q0 + w * 16 + 4 * lg + r;
        size_t ob = ((size_t)b * NSEQ + row) * DIMC + h * HDIM;
#pragma unroll
        for (int df = 0; df < 4; ++df) {
            u16 hh, ll;
            split_bf16(o[df][r] * inv, hh, ll);
            aoh[ob + df * 16 + l15] = hh;
            aol[ob + df * 16 + l15] = ll;
        }
    }
}

extern "C" void kernel_launch(void* const* d_in, const int* in_sizes, int n_in,
                              void* d_out, int out_size, void* d_ws, size_t ws_size,
                              hipStream_t stream) {
    const float* x     = (const float*)d_in[0];
    const float* elev  = (const float*)d_in[1];
    const float* wqkv  = (const float*)d_in[2];
    const float* wproj = (const float*)d_in[3];
    const float* bproj = (const float*)d_in[4];
    const float* alpha = (const float*)d_in[5];
    float* out = (float*)d_out;

    char* ws = (char*)d_ws;
    size_t off = 0;
    auto alloc = [&](size_t elems) {
        void* p = ws + off;
        off += (elems * 2 + 255) & ~(size_t)255;
        return (u16*)p;
    };
    const size_t szXW  = (size_t)MROWS * DIMC;
    const size_t szWQ  = (size_t)CQKV * DIMC;
    const size_t szWP  = (size_t)DIMC * DIMC;
    const size_t szQKV = (size_t)BATCH * NHEADS * NSEQ * HDIM;

    u16* xh  = alloc(szXW);  u16* xl  = alloc(szXW);
    u16* wqh = alloc(szWQ);  u16* wql = alloc(szWQ);
    u16* wph = alloc(szWP);  u16* wpl = alloc(szWP);
    u16* qh_ = alloc(szQKV); u16* ql_ = alloc(szQKV);
    u16* kh_ = alloc(szQKV); u16* kl_ = alloc(szQKV);
    u16* vth = alloc(szQKV); u16* vtl = alloc(szQKV);
    // attention output aliases x-split (x fully consumed by qkv GEMM before attn)
    u16* aoh = xh;
    u16* aol = xl;
    (void)ws_size; (void)in_sizes; (void)n_in; (void)out_size;

    split_kernel<<<(int)(szXW / 4 / 256), 256, 0, stream>>>(x, xh, xl, (int)(szXW / 4));
    split_kernel<<<(int)(szWQ / 4 / 256), 256, 0, stream>>>(wqkv, wqh, wql, (int)(szWQ / 4));
    split_kernel<<<(int)(szWP / 4 / 256), 256, 0, stream>>>(wproj, wph, wpl, (int)(szWP / 4));

    gemm_split<0><<<dim3(CQKV / 128, MROWS / 128), 256, 0, stream>>>(
        xh, xl, wqh, wql, DIMC, qh_, ql_, kh_, kl_, vth, vtl, nullptr, nullptr);

    attn_kernel<<<dim3(NSEQ / 64, BATCH * NHEADS), 256, 0, stream>>>(
        qh_, ql_, kh_, kl_, vth, vtl, elev, alpha, aoh, aol);

    gemm_split<1><<<dim3(DIMC / 128, MROWS / 128), 256, 0, stream>>>(
        aoh, aol, wph, wpl, DIMC, nullptr, nullptr, nullptr, nullptr, nullptr, nullptr,
        out, bproj);
}